// Round 13
// baseline (90.513 us; speedup 1.0000x reference)
//
#include <hip/hip_runtime.h>
#include <hip/hip_bf16.h>

#define B 16
#define S 2048
#define VOCAB 32000
#define D_EMB 256
#define D_MODEL 512
#define LN_EPS 1e-5f

using bf16x8 = __attribute__((ext_vector_type(8))) short;
using f32x4  = __attribute__((ext_vector_type(4))) float;

static __device__ __forceinline__ unsigned short f2bf(float f) {
    __hip_bfloat16 h = __float2bfloat16(f);   // RNE
    return *reinterpret_cast<unsigned short*>(&h);
}

static __device__ __forceinline__ bf16x8 pack8(f32x4 v0, f32x4 v1) {
    union { unsigned short us[8]; bf16x8 v; } pk;
    pk.us[0] = f2bf(v0.x); pk.us[1] = f2bf(v0.y);
    pk.us[2] = f2bf(v0.z); pk.us[3] = f2bf(v0.w);
    pk.us[4] = f2bf(v1.x); pk.us[5] = f2bf(v1.y);
    pk.us[6] = f2bf(v1.z); pk.us[7] = f2bf(v1.w);
    return pk.v;
}

// ---------------------------------------------------------------------------
// Kernel A (MFMA) — EXACT R5 form (measured: 23.1 µs ≈ its 21 µs Wb floor).
// ---------------------------------------------------------------------------
__global__ __launch_bounds__(256) void wk_mfma(
    const float* __restrict__ Wb,
    const float* __restrict__ king_table,
    const int* __restrict__ king_id,
    unsigned short* __restrict__ Wk)
{
    const int t    = threadIdx.x;
    const int lane = t & 63;
    const int wave = t >> 6;
    const int lr   = lane & 15;     // b index (B-frag col) / row index (A-frag)
    const int kg   = lane >> 4;     // k-group

    const int kid = king_id[lr];
    const float* kp = king_table + (size_t)kid * D_EMB + kg * 8;
    bf16x8 bemb[8];
#pragma unroll
    for (int step = 0; step < 8; ++step) {
        f32x4 v0 = *(const f32x4*)(kp + step * 32);
        f32x4 v1 = *(const f32x4*)(kp + step * 32 + 4);
        bemb[step] = pack8(v0, v1);
    }

    const int rbase = (blockIdx.x * 4 + wave) * 64;

#pragma unroll
    for (int mf = 0; mf < 4; ++mf) {
        const float* arow = Wb + (size_t)(rbase + mf * 16 + lr) * D_EMB + kg * 8;
        f32x4 acc = {};
#pragma unroll
        for (int step = 0; step < 8; ++step) {
            f32x4 v0 = *(const f32x4*)(arow + step * 32);
            f32x4 v1 = *(const f32x4*)(arow + step * 32 + 4);
            acc = __builtin_amdgcn_mfma_f32_16x16x32_bf16(
                pack8(v0, v1), bemb[step], acc, 0, 0, 0);
        }
        union { unsigned short us[4]; uint2 q; } st;
        st.us[0] = f2bf(acc[0]); st.us[1] = f2bf(acc[1]);
        st.us[2] = f2bf(acc[2]); st.us[3] = f2bf(acc[3]);
        *(uint2*)(Wk + (size_t)lr * (D_MODEL * D_EMB) + rbase + mf * 16 + kg * 4) = st.q;
    }
}

// ---------------------------------------------------------------------------
// Kernel B (MFMA) — EXACT R11 form (measured best: part of 59.3 µs total).
// Launched TWICE this round (idempotent) as an attribution probe:
//   total - 59.3 = T(B_warm)  -> structure-bound vs fetch-bound split.
// ---------------------------------------------------------------------------
#define TSB 64

__global__ __launch_bounds__(512, 4) void gemm_ln_mfma(
    const int* __restrict__ seq,
    const int* __restrict__ king_id,
    const float* __restrict__ token_tables,
    const unsigned short* __restrict__ Wk,
    const float* __restrict__ bb,
    const float* __restrict__ gamma,
    const float* __restrict__ beta,
    float* __restrict__ out)
{
    __shared__ unsigned short tokL[TSB][264];   // 64 x (256+8 pad) bf16 = 33 KB
    __shared__ float red_sum[8][TSB];
    __shared__ float red_sq[8][TSB];
    __shared__ float stats[2][TSB];             // [0]=mean, [1]=rstd

    // ---- XCD-aware decode: blocks with the same b pin to one XCD ----
    const int id   = blockIdx.x;
    const int xcd  = id & 7;
    const int k    = id >> 3;              // 0..63
    const int b    = xcd * 2 + (k >> 5);   // 2 batches per XCD
    const int tile = k & 31;

    const int s0   = tile * TSB;
    const int t    = threadIdx.x;
    const int lane = t & 63;
    const int wave = t >> 6;
    const int lr   = lane & 15;     // frag row/col index
    const int kg   = lane >> 4;     // k-group (0..3)

    const int kb = king_id[b];
    const float* ttab = token_tables + (size_t)kb * VOCAB * D_EMB;

    // staging geometry: thread t covers row = t>>3, k-chunk (t&7)*16 within
    // each 128-col half (16 floats = 4 dwordx4 per half).
    const int srow = t >> 3;
    const int sck  = (t & 7) * 16;
    const int tokidx = seq[b * S + s0 + srow];
    const float* srcrow = ttab + (size_t)tokidx * D_EMB + sck;

    // ---- phase 0: stage k-half 0 ([0,128)) ----
    {
        f32x4 v0 = *(const f32x4*)(srcrow + 0);
        f32x4 v1 = *(const f32x4*)(srcrow + 4);
        f32x4 v2 = *(const f32x4*)(srcrow + 8);
        f32x4 v3 = *(const f32x4*)(srcrow + 12);
        *(bf16x8*)&tokL[srow][sck]     = pack8(v0, v1);
        *(bf16x8*)&tokL[srow][sck + 8] = pack8(v2, v3);
    }
    __syncthreads();

    // ---- issue k-half 1 loads ([128,256)) -- held in regs across steps 0-3
    f32x4 h0 = *(const f32x4*)(srcrow + 128);
    f32x4 h1 = *(const f32x4*)(srcrow + 132);
    f32x4 h2 = *(const f32x4*)(srcrow + 136);
    f32x4 h3 = *(const f32x4*)(srcrow + 140);

    // ---- fragment pointers ----
    const int m0 = wave * 64;                  // wave's m-slice base
    const uint4* aptr[4];
    const uint4* bptr[4];
#pragma unroll
    for (int mf = 0; mf < 4; ++mf)
        aptr[mf] = (const uint4*)&tokL[mf * 16 + lr][kg * 8];
#pragma unroll
    for (int nf = 0; nf < 4; ++nf) {
        int col = m0 + nf * 16 + lr;
        bptr[nf] = (const uint4*)(Wk + ((size_t)(b * D_MODEL + col)) * D_EMB + kg * 8);
    }

    f32x4 acc[4][4] = {};

    // ---- K-steps 0-3 (k < 128, only half-0 of tokL touched) ----
#pragma unroll
    for (int step = 0; step < 4; ++step) {
        bf16x8 af[4], bfr[4];
#pragma unroll
        for (int mf = 0; mf < 4; ++mf) {
            uint4 q = aptr[mf][step * 4];
            af[mf] = __builtin_bit_cast(bf16x8, q);
        }
#pragma unroll
        for (int nf = 0; nf < 4; ++nf) {
            uint4 q = bptr[nf][step * 4];
            bfr[nf] = __builtin_bit_cast(bf16x8, q);
        }
#pragma unroll
        for (int mf = 0; mf < 4; ++mf)
#pragma unroll
            for (int nf = 0; nf < 4; ++nf)
                acc[mf][nf] = __builtin_amdgcn_mfma_f32_16x16x32_bf16(
                    af[mf], bfr[nf], acc[mf][nf], 0, 0, 0);
    }

    // ---- land k-half 1 into LDS, then finish K ----
    *(bf16x8*)&tokL[srow][128 + sck]     = pack8(h0, h1);
    *(bf16x8*)&tokL[srow][128 + sck + 8] = pack8(h2, h3);
    __syncthreads();

#pragma unroll
    for (int step = 4; step < 8; ++step) {
        bf16x8 af[4], bfr[4];
#pragma unroll
        for (int mf = 0; mf < 4; ++mf) {
            uint4 q = aptr[mf][step * 4];
            af[mf] = __builtin_bit_cast(bf16x8, q);
        }
#pragma unroll
        for (int nf = 0; nf < 4; ++nf) {
            uint4 q = bptr[nf][step * 4];
            bfr[nf] = __builtin_bit_cast(bf16x8, q);
        }
#pragma unroll
        for (int mf = 0; mf < 4; ++mf)
#pragma unroll
            for (int nf = 0; nf < 4; ++nf)
                acc[mf][nf] = __builtin_amdgcn_mfma_f32_16x16x32_bf16(
                    af[mf], bfr[nf], acc[mf][nf], 0, 0, 0);
    }

    // ---- epilogue: bias, block-wide LN stats ----
    float bbv[4], gv[4], bv[4];
#pragma unroll
    for (int nf = 0; nf < 4; ++nf) {
        int col = m0 + nf * 16 + lr;
        bbv[nf] = bb[col];
        gv[nf]  = gamma[col];
        bv[nf]  = beta[col];
    }

#pragma unroll
    for (int mf = 0; mf < 4; ++mf) {
#pragma unroll
        for (int r = 0; r < 4; ++r) {
            float sum = 0.0f, sq = 0.0f;
#pragma unroll
            for (int nf = 0; nf < 4; ++nf) {
                float v = acc[mf][nf][r] + bbv[nf];
                acc[mf][nf][r] = v;
                sum += v;
                sq  += v * v;
            }
#pragma unroll
            for (int off = 1; off < 16; off <<= 1) {
                sum += __shfl_xor(sum, off);
                sq  += __shfl_xor(sq, off);
            }
            if (lr == 0) {
                int row = mf * 16 + kg * 4 + r;
                red_sum[wave][row] = sum;
                red_sq[wave][row]  = sq;
            }
        }
    }
    __syncthreads();

    if (t < TSB) {
        float s = 0.0f, q = 0.0f;
#pragma unroll
        for (int w = 0; w < 8; ++w) { s += red_sum[w][t]; q += red_sq[w][t]; }
        float mean = s * (1.0f / D_MODEL);
        float var  = q * (1.0f / D_MODEL) - mean * mean;
        stats[0][t] = mean;
        stats[1][t] = rsqrtf(var + LN_EPS);
    }
    __syncthreads();

    // ---- normalize + store ----
#pragma unroll
    for (int mf = 0; mf < 4; ++mf) {
#pragma unroll
        for (int r = 0; r < 4; ++r) {
            int row = mf * 16 + kg * 4 + r;
            float mean = stats[0][row];
            float rstd = stats[1][row];
            float* op = out + ((size_t)b * S + s0 + row) * D_MODEL + m0 + lr;
#pragma unroll
            for (int nf = 0; nf < 4; ++nf)
                op[nf * 16] = (acc[mf][nf][r] - mean) * rstd * gv[nf] + bv[nf];
        }
    }
}

// ---------------------------------------------------------------------------
extern "C" void kernel_launch(void* const* d_in, const int* in_sizes, int n_in,
                              void* d_out, int out_size, void* d_ws, size_t ws_size,
                              hipStream_t stream)
{
    const int*   seq          = (const int*)d_in[0];
    const int*   king_id      = (const int*)d_in[1];
    const float* token_tables = (const float*)d_in[2];
    const float* Wb           = (const float*)d_in[3];
    const float* bb           = (const float*)d_in[4];
    const float* king_table   = (const float*)d_in[5];
    const float* gamma        = (const float*)d_in[6];
    const float* beta         = (const float*)d_in[7];
    float* out = (float*)d_out;

    unsigned short* Wk = (unsigned short*)d_ws;   // B*D_MODEL*D_EMB bf16 = 4 MB

    wk_mfma<<<dim3((D_MODEL * D_EMB) / 256), dim3(256), 0, stream>>>(
        Wb, king_table, king_id, Wk);
    // ATTRIBUTION PROBE: B launched twice (idempotent). total - 59.3 = B_warm.
    gemm_ln_mfma<<<dim3(S / TSB * B), dim3(512), 0, stream>>>(
        seq, king_id, token_tables, Wk, bb, gamma, beta, out);
    gemm_ln_mfma<<<dim3(S / TSB * B), dim3(512), 0, stream>>>(
        seq, king_id, token_tables, Wk, bb, gamma, beta, out);
}

// Round 15
// 63.007 us; speedup vs baseline: 1.4365x; 1.4365x over previous
//
#include <hip/hip_runtime.h>
#include <hip/hip_bf16.h>

#define B 16
#define S 2048
#define VOCAB 32000
#define D_EMB 256
#define D_MODEL 512
#define LN_EPS 1e-5f

using bf16x8 = __attribute__((ext_vector_type(8))) short;
using f32x4  = __attribute__((ext_vector_type(4))) float;

static __device__ __forceinline__ unsigned short f2bf(float f) {
    __hip_bfloat16 h = __float2bfloat16(f);   // RNE
    return *reinterpret_cast<unsigned short*>(&h);
}

static __device__ __forceinline__ bf16x8 pack8(f32x4 v0, f32x4 v1) {
    union { unsigned short us[8]; bf16x8 v; } pk;
    pk.us[0] = f2bf(v0.x); pk.us[1] = f2bf(v0.y);
    pk.us[2] = f2bf(v0.z); pk.us[3] = f2bf(v0.w);
    pk.us[4] = f2bf(v1.x); pk.us[5] = f2bf(v1.y);
    pk.us[6] = f2bf(v1.z); pk.us[7] = f2bf(v1.w);
    return pk.v;
}

// ---------------------------------------------------------------------------
// Kernel A (MFMA) — EXACT R5 form (measured: 23.1 µs ≈ its 21 µs Wb floor).
// ---------------------------------------------------------------------------
__global__ __launch_bounds__(256) void wk_mfma(
    const float* __restrict__ Wb,
    const float* __restrict__ king_table,
    const int* __restrict__ king_id,
    unsigned short* __restrict__ Wk)
{
    const int t    = threadIdx.x;
    const int lane = t & 63;
    const int wave = t >> 6;
    const int lr   = lane & 15;     // b index (B-frag col) / row index (A-frag)
    const int kg   = lane >> 4;     // k-group

    const int kid = king_id[lr];
    const float* kp = king_table + (size_t)kid * D_EMB + kg * 8;
    bf16x8 bemb[8];
#pragma unroll
    for (int step = 0; step < 8; ++step) {
        f32x4 v0 = *(const f32x4*)(kp + step * 32);
        f32x4 v1 = *(const f32x4*)(kp + step * 32 + 4);
        bemb[step] = pack8(v0, v1);
    }

    const int rbase = (blockIdx.x * 4 + wave) * 64;

#pragma unroll
    for (int mf = 0; mf < 4; ++mf) {
        const float* arow = Wb + (size_t)(rbase + mf * 16 + lr) * D_EMB + kg * 8;
        f32x4 acc = {};
#pragma unroll
        for (int step = 0; step < 8; ++step) {
            f32x4 v0 = *(const f32x4*)(arow + step * 32);
            f32x4 v1 = *(const f32x4*)(arow + step * 32 + 4);
            acc = __builtin_amdgcn_mfma_f32_16x16x32_bf16(
                pack8(v0, v1), bemb[step], acc, 0, 0, 0);
        }
        union { unsigned short us[4]; uint2 q; } st;
        st.us[0] = f2bf(acc[0]); st.us[1] = f2bf(acc[1]);
        st.us[2] = f2bf(acc[2]); st.us[3] = f2bf(acc[3]);
        *(uint2*)(Wk + (size_t)lr * (D_MODEL * D_EMB) + rbase + mf * 16 + kg * 4) = st.q;
    }
}

// ---------------------------------------------------------------------------
// Kernel B (MFMA) — R11 form with SWAPPED MFMA operands:
//   acc[nf][mf] = mfma(wk_frag[nf], tok_frag[mf], acc)   (A=Wk, B=tok)
// C transposes: lane holds s = s0+mf*16+lr (col) and m = m0+nf*16+kg*4+r
// (row) -> 4 CONSECUTIVE m per register quad. Epilogue: float4 stores
// (16/thread vs 64 scalar), 2-step shfl LN reduce (offsets 16,32),
// float4 gamma/beta/bias loads. Loads & staging byte-identical to R11.
// ---------------------------------------------------------------------------
#define TSB 64

__global__ __launch_bounds__(512, 4) void gemm_ln_mfma(
    const int* __restrict__ seq,
    const int* __restrict__ king_id,
    const float* __restrict__ token_tables,
    const unsigned short* __restrict__ Wk,
    const float* __restrict__ bb,
    const float* __restrict__ gamma,
    const float* __restrict__ beta,
    float* __restrict__ out)
{
    __shared__ unsigned short tokL[TSB][264];   // 64 x (256+8 pad) bf16 = 33 KB
    __shared__ float red_sum[8][TSB];
    __shared__ float red_sq[8][TSB];
    __shared__ float stats[2][TSB];             // [0]=mean, [1]=rstd

    // ---- XCD-aware decode: blocks with the same b pin to one XCD ----
    const int id   = blockIdx.x;
    const int xcd  = id & 7;
    const int k    = id >> 3;              // 0..63
    const int b    = xcd * 2 + (k >> 5);   // 2 batches per XCD
    const int tile = k & 31;

    const int s0   = tile * TSB;
    const int t    = threadIdx.x;
    const int lane = t & 63;
    const int wave = t >> 6;
    const int lr   = lane & 15;     // frag row/col index
    const int kg   = lane >> 4;     // k-group (0..3)

    const int kb = king_id[b];
    const float* ttab = token_tables + (size_t)kb * VOCAB * D_EMB;

    // staging geometry: thread t covers row = t>>3, k-chunk (t&7)*16 within
    // each 128-col half (16 floats = 4 dwordx4 per half).
    const int srow = t >> 3;
    const int sck  = (t & 7) * 16;
    const int tokidx = seq[b * S + s0 + srow];
    const float* srcrow = ttab + (size_t)tokidx * D_EMB + sck;

    // ---- phase 0: stage k-half 0 ([0,128)) ----
    {
        f32x4 v0 = *(const f32x4*)(srcrow + 0);
        f32x4 v1 = *(const f32x4*)(srcrow + 4);
        f32x4 v2 = *(const f32x4*)(srcrow + 8);
        f32x4 v3 = *(const f32x4*)(srcrow + 12);
        *(bf16x8*)&tokL[srow][sck]     = pack8(v0, v1);
        *(bf16x8*)&tokL[srow][sck + 8] = pack8(v2, v3);
    }
    __syncthreads();

    // ---- issue k-half 1 loads ([128,256)) -- held in regs across steps 0-3
    f32x4 h0 = *(const f32x4*)(srcrow + 128);
    f32x4 h1 = *(const f32x4*)(srcrow + 132);
    f32x4 h2 = *(const f32x4*)(srcrow + 136);
    f32x4 h3 = *(const f32x4*)(srcrow + 140);

    // ---- fragment pointers ----
    const int m0 = wave * 64;                  // wave's m-slice base
    const uint4* aptr[4];
    const uint4* bptr[4];
#pragma unroll
    for (int mf = 0; mf < 4; ++mf)
        aptr[mf] = (const uint4*)&tokL[mf * 16 + lr][kg * 8];
#pragma unroll
    for (int nf = 0; nf < 4; ++nf) {
        int col = m0 + nf * 16 + lr;
        bptr[nf] = (const uint4*)(Wk + ((size_t)(b * D_MODEL + col)) * D_EMB + kg * 8);
    }

    // acc[nf][mf]: m-frag nf (A-operand=Wk), s-frag mf (B-operand=tok)
    f32x4 acc[4][4] = {};

    // ---- K-steps 0-3 (k < 128, only half-0 of tokL touched) ----
#pragma unroll
    for (int step = 0; step < 4; ++step) {
        bf16x8 af[4], bfr[4];
#pragma unroll
        for (int mf = 0; mf < 4; ++mf) {
            uint4 q = aptr[mf][step * 4];
            af[mf] = __builtin_bit_cast(bf16x8, q);
        }
#pragma unroll
        for (int nf = 0; nf < 4; ++nf) {
            uint4 q = bptr[nf][step * 4];
            bfr[nf] = __builtin_bit_cast(bf16x8, q);
        }
#pragma unroll
        for (int nf = 0; nf < 4; ++nf)
#pragma unroll
            for (int mf = 0; mf < 4; ++mf)
                acc[nf][mf] = __builtin_amdgcn_mfma_f32_16x16x32_bf16(
                    bfr[nf], af[mf], acc[nf][mf], 0, 0, 0);
    }

    // ---- land k-half 1 into LDS, then finish K ----
    *(bf16x8*)&tokL[srow][128 + sck]     = pack8(h0, h1);
    *(bf16x8*)&tokL[srow][128 + sck + 8] = pack8(h2, h3);
    __syncthreads();

#pragma unroll
    for (int step = 4; step < 8; ++step) {
        bf16x8 af[4], bfr[4];
#pragma unroll
        for (int mf = 0; mf < 4; ++mf) {
            uint4 q = aptr[mf][step * 4];
            af[mf] = __builtin_bit_cast(bf16x8, q);
        }
#pragma unroll
        for (int nf = 0; nf < 4; ++nf) {
            uint4 q = bptr[nf][step * 4];
            bfr[nf] = __builtin_bit_cast(bf16x8, q);
        }
#pragma unroll
        for (int nf = 0; nf < 4; ++nf)
#pragma unroll
            for (int mf = 0; mf < 4; ++mf)
                acc[nf][mf] = __builtin_amdgcn_mfma_f32_16x16x32_bf16(
                    bfr[nf], af[mf], acc[nf][mf], 0, 0, 0);
    }

    // ---- epilogue: bias (float4), LN stats over m ----
    f32x4 bb4[4], g4[4], be4[4];
#pragma unroll
    for (int nf = 0; nf < 4; ++nf) {
        int mcol = m0 + nf * 16 + kg * 4;
        bb4[nf] = *(const f32x4*)(bb    + mcol);
        g4[nf]  = *(const f32x4*)(gamma + mcol);
        be4[nf] = *(const f32x4*)(beta  + mcol);
    }

    // per s-frag mf: lane's 16 m-values (nf x r), reduce across kg groups
#pragma unroll
    for (int mf = 0; mf < 4; ++mf) {
        float sum = 0.0f, sq = 0.0f;
#pragma unroll
        for (int nf = 0; nf < 4; ++nf) {
#pragma unroll
            for (int r = 0; r < 4; ++r) {
                float v = acc[nf][mf][r] + bb4[nf][r];
                acc[nf][mf][r] = v;
                sum += v;
                sq  += v * v;
            }
        }
        sum += __shfl_xor(sum, 16); sq += __shfl_xor(sq, 16);
        sum += __shfl_xor(sum, 32); sq += __shfl_xor(sq, 32);
        if (kg == 0) {
            int row = mf * 16 + lr;          // s-row within tile
            red_sum[wave][row] = sum;
            red_sq[wave][row]  = sq;
        }
    }
    __syncthreads();

    if (t < TSB) {
        float s = 0.0f, q = 0.0f;
#pragma unroll
        for (int w = 0; w < 8; ++w) { s += red_sum[w][t]; q += red_sq[w][t]; }
        float mean = s * (1.0f / D_MODEL);
        float var  = q * (1.0f / D_MODEL) - mean * mean;
        stats[0][t] = mean;
        stats[1][t] = rsqrtf(var + LN_EPS);
    }
    __syncthreads();

    // ---- normalize + float4 stores (4 consecutive m per quad) ----
#pragma unroll
    for (int mf = 0; mf < 4; ++mf) {
        int row = mf * 16 + lr;              // s-row within tile
        float mean = stats[0][row];
        float rstd = stats[1][row];
        float* op = out + ((size_t)b * S + s0 + row) * D_MODEL + m0 + kg * 4;
#pragma unroll
        for (int nf = 0; nf < 4; ++nf) {
            f32x4 o;
#pragma unroll
            for (int r = 0; r < 4; ++r)
                o[r] = (acc[nf][mf][r] - mean) * rstd * g4[nf][r] + be4[nf][r];
            *(f32x4*)(op + nf * 16) = o;
        }
    }
}

// ---------------------------------------------------------------------------
extern "C" void kernel_launch(void* const* d_in, const int* in_sizes, int n_in,
                              void* d_out, int out_size, void* d_ws, size_t ws_size,
                              hipStream_t stream)
{
    const int*   seq          = (const int*)d_in[0];
    const int*   king_id      = (const int*)d_in[1];
    const float* token_tables = (const float*)d_in[2];
    const float* Wb           = (const float*)d_in[3];
    const float* bb           = (const float*)d_in[4];
    const float* king_table   = (const float*)d_in[5];
    const float* gamma        = (const float*)d_in[6];
    const float* beta         = (const float*)d_in[7];
    float* out = (float*)d_out;

    unsigned short* Wk = (unsigned short*)d_ws;   // B*D_MODEL*D_EMB bf16 = 4 MB

    wk_mfma<<<dim3((D_MODEL * D_EMB) / 256), dim3(256), 0, stream>>>(
        Wb, king_table, king_id, Wk);
    gemm_ln_mfma<<<dim3(S / TSB * B), dim3(512), 0, stream>>>(
        seq, king_id, token_tables, Wk, bb, gamma, beta, out);
}

// Round 16
// 59.122 us; speedup vs baseline: 1.5309x; 1.0657x over previous
//
#include <hip/hip_runtime.h>
#include <hip/hip_bf16.h>

#define B 16
#define S 2048
#define VOCAB 32000
#define D_EMB 256
#define D_MODEL 512
#define LN_EPS 1e-5f

using bf16x8 = __attribute__((ext_vector_type(8))) short;
using f32x4  = __attribute__((ext_vector_type(4))) float;

static __device__ __forceinline__ unsigned short f2bf(float f) {
    __hip_bfloat16 h = __float2bfloat16(f);   // RNE
    return *reinterpret_cast<unsigned short*>(&h);
}

static __device__ __forceinline__ bf16x8 pack8(f32x4 v0, f32x4 v1) {
    union { unsigned short us[8]; bf16x8 v; } pk;
    pk.us[0] = f2bf(v0.x); pk.us[1] = f2bf(v0.y);
    pk.us[2] = f2bf(v0.z); pk.us[3] = f2bf(v0.w);
    pk.us[4] = f2bf(v1.x); pk.us[5] = f2bf(v1.y);
    pk.us[6] = f2bf(v1.z); pk.us[7] = f2bf(v1.w);
    return pk.v;
}

// Fragment-order Wk layout: flat(b,m,i) = b*131072 + (m>>4)*4096
//   + (i>>5)*512 + ((i>>3)&3)*128 + (m&15)*8 + (i&7)
// -> B's per-(wave,nf,step) fragment load is base + lane*8: 1KB coalesced.

// ---------------------------------------------------------------------------
// Kernel A (MFMA) — R5 compute, fragment-order Wk store.
// ---------------------------------------------------------------------------
__global__ __launch_bounds__(256) void wk_mfma(
    const float* __restrict__ Wb,
    const float* __restrict__ king_table,
    const int* __restrict__ king_id,
    unsigned short* __restrict__ Wk)
{
    const int t    = threadIdx.x;
    const int lane = t & 63;
    const int wave = t >> 6;
    const int lr   = lane & 15;     // b index (B-frag col) / row index (A-frag)
    const int kg   = lane >> 4;     // k-group

    const int kid = king_id[lr];
    const float* kp = king_table + (size_t)kid * D_EMB + kg * 8;
    bf16x8 bemb[8];
#pragma unroll
    for (int step = 0; step < 8; ++step) {
        f32x4 v0 = *(const f32x4*)(kp + step * 32);
        f32x4 v1 = *(const f32x4*)(kp + step * 32 + 4);
        bemb[step] = pack8(v0, v1);
    }

    const int rbase = (blockIdx.x * 4 + wave) * 64;
    const int m     = rbase >> 8;          // Wb row slab -> (m, i-slab)
    const int ib    = rbase & 255;

#pragma unroll
    for (int mf = 0; mf < 4; ++mf) {
        const float* arow = Wb + (size_t)(rbase + mf * 16 + lr) * D_EMB + kg * 8;
        f32x4 acc = {};
#pragma unroll
        for (int step = 0; step < 8; ++step) {
            f32x4 v0 = *(const f32x4*)(arow + step * 32);
            f32x4 v1 = *(const f32x4*)(arow + step * 32 + 4);
            acc = __builtin_amdgcn_mfma_f32_16x16x32_bf16(
                pack8(v0, v1), bemb[step], acc, 0, 0, 0);
        }
        // lane holds Wk[b=lr][m][i0..i0+3], i0 = ib + mf*16 + kg*4
        union { unsigned short us[4]; uint2 q; } st;
        st.us[0] = f2bf(acc[0]); st.us[1] = f2bf(acc[1]);
        st.us[2] = f2bf(acc[2]); st.us[3] = f2bf(acc[3]);
        const int i0 = ib + mf * 16 + kg * 4;
        size_t widx = (size_t)lr * 131072 + (size_t)(m >> 4) * 4096
                    + (i0 >> 5) * 512 + ((i0 >> 3) & 3) * 128
                    + (m & 15) * 8 + (i0 & 7);
        *(uint2*)(Wk + widx) = st.q;
    }
}

// ---------------------------------------------------------------------------
// Kernel B (MFMA) — EXACT R11 structure; only bptr uses the fragment-order
// layout: one coalesced 1KB load per (nf, step) instead of 16-seg scatter.
// ---------------------------------------------------------------------------
#define TSB 64

__global__ __launch_bounds__(512, 4) void gemm_ln_mfma(
    const int* __restrict__ seq,
    const int* __restrict__ king_id,
    const float* __restrict__ token_tables,
    const unsigned short* __restrict__ Wk,
    const float* __restrict__ bb,
    const float* __restrict__ gamma,
    const float* __restrict__ beta,
    float* __restrict__ out)
{
    __shared__ unsigned short tokL[TSB][264];   // 64 x (256+8 pad) bf16 = 33 KB
    __shared__ float red_sum[8][TSB];
    __shared__ float red_sq[8][TSB];
    __shared__ float stats[2][TSB];             // [0]=mean, [1]=rstd

    // ---- XCD-aware decode: blocks with the same b pin to one XCD ----
    const int id   = blockIdx.x;
    const int xcd  = id & 7;
    const int k    = id >> 3;              // 0..63
    const int b    = xcd * 2 + (k >> 5);   // 2 batches per XCD
    const int tile = k & 31;

    const int s0   = tile * TSB;
    const int t    = threadIdx.x;
    const int lane = t & 63;
    const int wave = t >> 6;
    const int lr   = lane & 15;     // frag row/col index
    const int kg   = lane >> 4;     // k-group (0..3)

    const int kb = king_id[b];
    const float* ttab = token_tables + (size_t)kb * VOCAB * D_EMB;

    // staging geometry: thread t covers row = t>>3, k-chunk (t&7)*16 within
    // each 128-col half (16 floats = 4 dwordx4 per half).
    const int srow = t >> 3;
    const int sck  = (t & 7) * 16;
    const int tokidx = seq[b * S + s0 + srow];
    const float* srcrow = ttab + (size_t)tokidx * D_EMB + sck;

    // ---- phase 0: stage k-half 0 ([0,128)) ----
    {
        f32x4 v0 = *(const f32x4*)(srcrow + 0);
        f32x4 v1 = *(const f32x4*)(srcrow + 4);
        f32x4 v2 = *(const f32x4*)(srcrow + 8);
        f32x4 v3 = *(const f32x4*)(srcrow + 12);
        *(bf16x8*)&tokL[srow][sck]     = pack8(v0, v1);
        *(bf16x8*)&tokL[srow][sck + 8] = pack8(v2, v3);
    }
    __syncthreads();

    // ---- issue k-half 1 loads ([128,256)) -- held in regs across steps 0-3
    f32x4 h0 = *(const f32x4*)(srcrow + 128);
    f32x4 h1 = *(const f32x4*)(srcrow + 132);
    f32x4 h2 = *(const f32x4*)(srcrow + 136);
    f32x4 h3 = *(const f32x4*)(srcrow + 140);

    // ---- fragment pointers ----
    const int m0 = wave * 64;                  // wave's m-slice base
    const uint4* aptr[4];
    const uint4* bptr[4];
#pragma unroll
    for (int mf = 0; mf < 4; ++mf)
        aptr[mf] = (const uint4*)&tokL[mf * 16 + lr][kg * 8];
#pragma unroll
    for (int nf = 0; nf < 4; ++nf) {
        // fragment-order: base + lane*8 elems; step stride = 512 elems
        bptr[nf] = (const uint4*)(Wk + (size_t)b * 131072
                                  + (size_t)(wave * 4 + nf) * 4096 + lane * 8);
    }

    f32x4 acc[4][4] = {};

    // ---- K-steps 0-3 (k < 128, only half-0 of tokL touched) ----
#pragma unroll
    for (int step = 0; step < 4; ++step) {
        bf16x8 af[4], bfr[4];
#pragma unroll
        for (int mf = 0; mf < 4; ++mf) {
            uint4 q = aptr[mf][step * 4];
            af[mf] = __builtin_bit_cast(bf16x8, q);
        }
#pragma unroll
        for (int nf = 0; nf < 4; ++nf) {
            uint4 q = bptr[nf][step * 64];
            bfr[nf] = __builtin_bit_cast(bf16x8, q);
        }
#pragma unroll
        for (int mf = 0; mf < 4; ++mf)
#pragma unroll
            for (int nf = 0; nf < 4; ++nf)
                acc[mf][nf] = __builtin_amdgcn_mfma_f32_16x16x32_bf16(
                    af[mf], bfr[nf], acc[mf][nf], 0, 0, 0);
    }

    // ---- land k-half 1 into LDS, then finish K ----
    *(bf16x8*)&tokL[srow][128 + sck]     = pack8(h0, h1);
    *(bf16x8*)&tokL[srow][128 + sck + 8] = pack8(h2, h3);
    __syncthreads();

#pragma unroll
    for (int step = 4; step < 8; ++step) {
        bf16x8 af[4], bfr[4];
#pragma unroll
        for (int mf = 0; mf < 4; ++mf) {
            uint4 q = aptr[mf][step * 4];
            af[mf] = __builtin_bit_cast(bf16x8, q);
        }
#pragma unroll
        for (int nf = 0; nf < 4; ++nf) {
            uint4 q = bptr[nf][step * 64];
            bfr[nf] = __builtin_bit_cast(bf16x8, q);
        }
#pragma unroll
        for (int mf = 0; mf < 4; ++mf)
#pragma unroll
            for (int nf = 0; nf < 4; ++nf)
                acc[mf][nf] = __builtin_amdgcn_mfma_f32_16x16x32_bf16(
                    af[mf], bfr[nf], acc[mf][nf], 0, 0, 0);
    }

    // ---- epilogue: bias, block-wide LN stats ----
    float bbv[4], gv[4], bv[4];
#pragma unroll
    for (int nf = 0; nf < 4; ++nf) {
        int col = m0 + nf * 16 + lr;
        bbv[nf] = bb[col];
        gv[nf]  = gamma[col];
        bv[nf]  = beta[col];
    }

#pragma unroll
    for (int mf = 0; mf < 4; ++mf) {
#pragma unroll
        for (int r = 0; r < 4; ++r) {
            float sum = 0.0f, sq = 0.0f;
#pragma unroll
            for (int nf = 0; nf < 4; ++nf) {
                float v = acc[mf][nf][r] + bbv[nf];
                acc[mf][nf][r] = v;
                sum += v;
                sq  += v * v;
            }
#pragma unroll
            for (int off = 1; off < 16; off <<= 1) {
                sum += __shfl_xor(sum, off);
                sq  += __shfl_xor(sq, off);
            }
            if (lr == 0) {
                int row = mf * 16 + kg * 4 + r;
                red_sum[wave][row] = sum;
                red_sq[wave][row]  = sq;
            }
        }
    }
    __syncthreads();

    if (t < TSB) {
        float s = 0.0f, q = 0.0f;
#pragma unroll
        for (int w = 0; w < 8; ++w) { s += red_sum[w][t]; q += red_sq[w][t]; }
        float mean = s * (1.0f / D_MODEL);
        float var  = q * (1.0f / D_MODEL) - mean * mean;
        stats[0][t] = mean;
        stats[1][t] = rsqrtf(var + LN_EPS);
    }
    __syncthreads();

    // ---- normalize + store ----
#pragma unroll
    for (int mf = 0; mf < 4; ++mf) {
#pragma unroll
        for (int r = 0; r < 4; ++r) {
            int row = mf * 16 + kg * 4 + r;
            float mean = stats[0][row];
            float rstd = stats[1][row];
            float* op = out + ((size_t)b * S + s0 + row) * D_MODEL + m0 + lr;
#pragma unroll
            for (int nf = 0; nf < 4; ++nf)
                op[nf * 16] = (acc[mf][nf][r] - mean) * rstd * gv[nf] + bv[nf];
        }
    }
}

// ---------------------------------------------------------------------------
extern "C" void kernel_launch(void* const* d_in, const int* in_sizes, int n_in,
                              void* d_out, int out_size, void* d_ws, size_t ws_size,
                              hipStream_t stream)
{
    const int*   seq          = (const int*)d_in[0];
    const int*   king_id      = (const int*)d_in[1];
    const float* token_tables = (const float*)d_in[2];
    const float* Wb           = (const float*)d_in[3];
    const float* bb           = (const float*)d_in[4];
    const float* king_table   = (const float*)d_in[5];
    const float* gamma        = (const float*)d_in[6];
    const float* beta         = (const float*)d_in[7];
    float* out = (float*)d_out;

    unsigned short* Wk = (unsigned short*)d_ws;   // 4 MB, fragment-order layout

    wk_mfma<<<dim3((D_MODEL * D_EMB) / 256), dim3(256), 0, stream>>>(
        Wb, king_table, king_id, Wk);
    gemm_ln_mfma<<<dim3(S / TSB * B), dim3(512), 0, stream>>>(
        seq, king_id, token_tables, Wk, bb, gamma, beta, out);
}